// Round 2
// baseline (63.476 us; speedup 1.0000x reference)
//
#include <hip/hip_runtime.h>

#define NT 128

__device__ __forceinline__ void st4(float* dst, float4 v) {
    dst[0] = v.x; dst[1] = v.y; dst[2] = v.z; dst[3] = v.w;
}
__device__ __forceinline__ float4 ld4(const float* s) {
    return make_float4(s[0], s[1], s[2], s[3]);
}

// acc = X @ Y   (8x8, k=0 is mul not fma: no zero-init pass needed)
__device__ __forceinline__ void mm_mul(float (&acc)[64], const float (&X)[64], const float (&Y)[64]) {
#pragma unroll
    for (int i = 0; i < 8; ++i) {
        {
            const float x = X[i * 8 + 0];
#pragma unroll
            for (int j = 0; j < 8; ++j) acc[i * 8 + j] = x * Y[0 * 8 + j];
        }
#pragma unroll
        for (int k = 1; k < 8; ++k) {
            const float x = X[i * 8 + k];
#pragma unroll
            for (int j = 0; j < 8; ++j)
                acc[i * 8 + j] = fmaf(x, Y[k * 8 + j], acc[i * 8 + j]);
        }
    }
}
// acc += X @ Y
__device__ __forceinline__ void mm_add(float (&acc)[64], const float (&X)[64], const float (&Y)[64]) {
#pragma unroll
    for (int i = 0; i < 8; ++i) {
#pragma unroll
        for (int k = 0; k < 8; ++k) {
            const float x = X[i * 8 + k];
#pragma unroll
            for (int j = 0; j < 8; ++j)
                acc[i * 8 + j] = fmaf(x, Y[k * 8 + j], acc[i * 8 + j]);
        }
    }
}
// acc -= X @ Y
__device__ __forceinline__ void mm_sub(float (&acc)[64], const float (&X)[64], const float (&Y)[64]) {
#pragma unroll
    for (int i = 0; i < 8; ++i) {
#pragma unroll
        for (int k = 0; k < 8; ++k) {
            const float x = -X[i * 8 + k];
#pragma unroll
            for (int j = 0; j < 8; ++j)
                acc[i * 8 + j] = fmaf(x, Y[k * 8 + j], acc[i * 8 + j]);
        }
    }
}

__global__ __launch_bounds__(NT, 2)
void magnus6_kernel(const float* __restrict__ A,
                    const float* __restrict__ hp,
                    const float* __restrict__ y0,
                    float* __restrict__ out,
                    int B)
{
    // ONE per-thread-private spill slot (alpha3 only): 256 B/thread, 32 KB/block.
    // Column tx of each [chunk][NT] slab; no cross-thread sharing, no barriers.
    __shared__ float4 lds[16][NT];   // 32 KB

    const int tx  = threadIdx.x;
    const int tid = blockIdx.x * NT + tx;
    if (tid >= B) return;

    const float h    = hp[0];
    const float c_a2 = h * 1.2909944487358056f;   // h*sqrt(15)/3
    const float c_a3 = h * (10.0f / 3.0f);
    const float c_m  = 20.0f / 3.0f;

    const float4* __restrict__ Ap =
        reinterpret_cast<const float4*>(A + (size_t)tid * 192);

    float R1[64];   // alpha1 -> Omega0 -> Omega
    float R2[64];   // A1 -> alpha2 -> Q (commutator accumulated in place)
    float R3[64];   // C1 -> T' = (C1+2a3)/60 -> P' = term_in_comm/240

    // ---- load A1 -> R2 ----
#pragma unroll
    for (int c = 0; c < 16; ++c) st4(&R2[4 * c], Ap[c]);
    // ---- load A2, R1 = h*A2 = alpha1 ----
#pragma unroll
    for (int c = 0; c < 16; ++c) {
        float4 v = Ap[16 + c];
        R1[4 * c + 0] = h * v.x; R1[4 * c + 1] = h * v.y;
        R1[4 * c + 2] = h * v.z; R1[4 * c + 3] = h * v.w;
    }
    // ---- stream A3: alpha3 -> LDS ; alpha2 overwrites A1 in R2 ----
#pragma unroll
    for (int c = 0; c < 16; ++c) {
        float4 v = Ap[32 + c];
        float vv[4]; st4(vv, v);
        float w[4];
#pragma unroll
        for (int j = 0; j < 4; ++j) {
            const int idx = 4 * c + j;
            const float A1e = R2[idx];
            const float A3e = vv[j];
            w[j]    = c_a3 * (A1e + A3e) - c_m * R1[idx];  // alpha3 = h*10/3*(A1-2A2+A3)
            R2[idx] = c_a2 * (A3e - A1e);                  // alpha2
        }
        lds[c][tx] = ld4(w);
    }

    // ---- C1 = [alpha1, alpha2] into R3 ----
    mm_mul(R3, R1, R2);
    mm_sub(R3, R2, R1);

    // ---- T' = (C1 + 2*alpha3)/60  (in place; alpha3 streamed from LDS) ----
#pragma unroll
    for (int c = 0; c < 16; ++c) {
        float vv[4]; st4(vv, lds[c][tx]);
#pragma unroll
        for (int j = 0; j < 4; ++j) {
            const int idx = 4 * c + j;
            R3[idx] = fmaf(R3[idx], (1.0f / 60.0f), (1.0f / 30.0f) * vv[j]);
        }
    }

    // ---- Q = alpha2 - alpha1@T' + T'@alpha1  (accumulate in place into R2) ----
    //      (C2 = -(1/60)[alpha1, T] = -[alpha1, T'])
    mm_sub(R2, R1, R3);
    mm_add(R2, R3, R1);

    // ---- P' = T'/4 - alpha1/12 - alpha3/80  (into R3);
    //      Omega0 = alpha1 + alpha3/12        (into R1); alpha3 read once ----
#pragma unroll
    for (int c = 0; c < 16; ++c) {
        float vv[4]; st4(vv, lds[c][tx]);
#pragma unroll
        for (int j = 0; j < 4; ++j) {
            const int idx = 4 * c + j;
            const float a3e = vv[j];
            const float a1e = R1[idx];
            R3[idx] = 0.25f * R3[idx] - (1.0f / 12.0f) * a1e - (1.0f / 80.0f) * a3e;
            R1[idx] = a1e + (1.0f / 12.0f) * a3e;
        }
    }

    // ---- Omega = Omega0 + P'@Q - Q@P'  (accumulate into R1) ----
    mm_add(R1, R3, R2);
    mm_sub(R1, R2, R3);

    // ---- y = expm(Omega) @ y0 via Taylor matvecs (order 6) ----
    const float4* __restrict__ y0p =
        reinterpret_cast<const float4*>(y0 + (size_t)tid * 8);
    float v[8], y[8];
    st4(&v[0], y0p[0]); st4(&v[4], y0p[1]);
#pragma unroll
    for (int i = 0; i < 8; ++i) y[i] = v[i];

    const float inv[6] = {1.0f, 0.5f, 1.0f / 3.0f, 0.25f, 0.2f, 1.0f / 6.0f};
#pragma unroll
    for (int k = 0; k < 6; ++k) {
        float w[8];
#pragma unroll
        for (int i = 0; i < 8; ++i) {
            float s = 0.0f;
#pragma unroll
            for (int j = 0; j < 8; ++j) s = fmaf(R1[i * 8 + j], v[j], s);
            w[i] = s * inv[k];
        }
#pragma unroll
        for (int i = 0; i < 8; ++i) { v[i] = w[i]; y[i] += v[i]; }
    }

    float4* __restrict__ op = reinterpret_cast<float4*>(out + (size_t)tid * 8);
    op[0] = make_float4(y[0], y[1], y[2], y[3]);
    op[1] = make_float4(y[4], y[5], y[6], y[7]);
}

extern "C" void kernel_launch(void* const* d_in, const int* in_sizes, int n_in,
                              void* d_out, int out_size, void* d_ws, size_t ws_size,
                              hipStream_t stream)
{
    const float* A  = (const float*)d_in[0];
    const float* hp = (const float*)d_in[1];
    const float* y0 = (const float*)d_in[2];
    float* out = (float*)d_out;

    const int B = in_sizes[2] / 8;   // y0 is (B, 8)
    const int grid = (B + NT - 1) / NT;
    magnus6_kernel<<<grid, NT, 0, stream>>>(A, hp, y0, out, B);
}

// Round 3
// 51.327 us; speedup vs baseline: 1.2367x; 1.2367x over previous
//
#include <hip/hip_runtime.h>

#define NT 128

__device__ __forceinline__ void st4(float* dst, float4 v) {
    dst[0] = v.x; dst[1] = v.y; dst[2] = v.z; dst[3] = v.w;
}
__device__ __forceinline__ float4 ld4(const float* s) {
    return make_float4(s[0], s[1], s[2], s[3]);
}

// acc = X @ Y   (8x8, k=0 is mul not fma: no zero-init pass needed)
__device__ __forceinline__ void mm_mul(float (&acc)[64], const float (&X)[64], const float (&Y)[64]) {
#pragma unroll
    for (int i = 0; i < 8; ++i) {
        {
            const float x = X[i * 8 + 0];
#pragma unroll
            for (int j = 0; j < 8; ++j) acc[i * 8 + j] = x * Y[0 * 8 + j];
        }
#pragma unroll
        for (int k = 1; k < 8; ++k) {
            const float x = X[i * 8 + k];
#pragma unroll
            for (int j = 0; j < 8; ++j)
                acc[i * 8 + j] = fmaf(x, Y[k * 8 + j], acc[i * 8 + j]);
        }
    }
}
// acc += X @ Y
__device__ __forceinline__ void mm_add(float (&acc)[64], const float (&X)[64], const float (&Y)[64]) {
#pragma unroll
    for (int i = 0; i < 8; ++i) {
#pragma unroll
        for (int k = 0; k < 8; ++k) {
            const float x = X[i * 8 + k];
#pragma unroll
            for (int j = 0; j < 8; ++j)
                acc[i * 8 + j] = fmaf(x, Y[k * 8 + j], acc[i * 8 + j]);
        }
    }
}
// acc -= X @ Y
__device__ __forceinline__ void mm_sub(float (&acc)[64], const float (&X)[64], const float (&Y)[64]) {
#pragma unroll
    for (int i = 0; i < 8; ++i) {
#pragma unroll
        for (int k = 0; k < 8; ++k) {
            const float x = -X[i * 8 + k];
#pragma unroll
            for (int j = 0; j < 8; ++j)
                acc[i * 8 + j] = fmaf(x, Y[k * 8 + j], acc[i * 8 + j]);
        }
    }
}

__global__ __launch_bounds__(NT)
__attribute__((amdgpu_waves_per_eu(2, 2)))   // pin 2 waves/EU: VGPR budget 256, no spill
void magnus6_kernel(const float* __restrict__ A,
                    const float* __restrict__ hp,
                    const float* __restrict__ y0,
                    float* __restrict__ out,
                    int B)
{
    // ONE per-thread-private spill slot (alpha3 only): 256 B/thread, 32 KB/block.
    // Column tx of each [chunk][NT] slab; no cross-thread sharing, no barriers.
    __shared__ float4 lds[16][NT];   // 32 KB

    const int tx  = threadIdx.x;
    const int tid = blockIdx.x * NT + tx;
    if (tid >= B) return;

    const float h    = hp[0];
    const float c_a2 = h * 1.2909944487358056f;   // h*sqrt(15)/3
    const float c_a3 = h * (10.0f / 3.0f);
    const float c_m  = 20.0f / 3.0f;

    const float4* __restrict__ Ap =
        reinterpret_cast<const float4*>(A + (size_t)tid * 192);

    float R1[64];   // alpha1 -> Omega0 -> Omega
    float R2[64];   // A1 -> alpha2 -> Q (commutator accumulated in place)
    float R3[64];   // C1 -> T' = (C1+2a3)/60 -> P' = term_in_comm/240

    // ---- load A1 -> R2 ----
#pragma unroll
    for (int c = 0; c < 16; ++c) st4(&R2[4 * c], Ap[c]);
    // ---- load A2, R1 = h*A2 = alpha1 ----
#pragma unroll
    for (int c = 0; c < 16; ++c) {
        float4 v = Ap[16 + c];
        R1[4 * c + 0] = h * v.x; R1[4 * c + 1] = h * v.y;
        R1[4 * c + 2] = h * v.z; R1[4 * c + 3] = h * v.w;
    }
    // ---- stream A3: alpha3 -> LDS ; alpha2 overwrites A1 in R2 ----
#pragma unroll
    for (int c = 0; c < 16; ++c) {
        float4 v = Ap[32 + c];
        float vv[4]; st4(vv, v);
        float w[4];
#pragma unroll
        for (int j = 0; j < 4; ++j) {
            const int idx = 4 * c + j;
            const float A1e = R2[idx];
            const float A3e = vv[j];
            w[j]    = c_a3 * (A1e + A3e) - c_m * R1[idx];  // alpha3 = h*10/3*(A1-2A2+A3)
            R2[idx] = c_a2 * (A3e - A1e);                  // alpha2
        }
        lds[c][tx] = ld4(w);
    }

    // ---- C1 = [alpha1, alpha2] into R3 ----
    mm_mul(R3, R1, R2);
    mm_sub(R3, R2, R1);

    // ---- T' = (C1 + 2*alpha3)/60  (in place; alpha3 streamed from LDS) ----
#pragma unroll
    for (int c = 0; c < 16; ++c) {
        float vv[4]; st4(vv, lds[c][tx]);
#pragma unroll
        for (int j = 0; j < 4; ++j) {
            const int idx = 4 * c + j;
            R3[idx] = fmaf(R3[idx], (1.0f / 60.0f), (1.0f / 30.0f) * vv[j]);
        }
    }

    // ---- Q = alpha2 - alpha1@T' + T'@alpha1  (accumulate in place into R2) ----
    //      (C2 = -(1/60)[alpha1, T] = -[alpha1, T'])
    mm_sub(R2, R1, R3);
    mm_add(R2, R3, R1);

    // ---- P' = T'/4 - alpha1/12 - alpha3/80  (into R3);
    //      Omega0 = alpha1 + alpha3/12        (into R1); alpha3 read once ----
#pragma unroll
    for (int c = 0; c < 16; ++c) {
        float vv[4]; st4(vv, lds[c][tx]);
#pragma unroll
        for (int j = 0; j < 4; ++j) {
            const int idx = 4 * c + j;
            const float a3e = vv[j];
            const float a1e = R1[idx];
            R3[idx] = 0.25f * R3[idx] - (1.0f / 12.0f) * a1e - (1.0f / 80.0f) * a3e;
            R1[idx] = a1e + (1.0f / 12.0f) * a3e;
        }
    }

    // ---- Omega = Omega0 + P'@Q - Q@P'  (accumulate into R1) ----
    mm_add(R1, R3, R2);
    mm_sub(R1, R2, R3);

    // ---- y = expm(Omega) @ y0 via Taylor matvecs (order 6) ----
    const float4* __restrict__ y0p =
        reinterpret_cast<const float4*>(y0 + (size_t)tid * 8);
    float v[8], y[8];
    st4(&v[0], y0p[0]); st4(&v[4], y0p[1]);
#pragma unroll
    for (int i = 0; i < 8; ++i) y[i] = v[i];

    const float inv[6] = {1.0f, 0.5f, 1.0f / 3.0f, 0.25f, 0.2f, 1.0f / 6.0f};
#pragma unroll
    for (int k = 0; k < 6; ++k) {
        float w[8];
#pragma unroll
        for (int i = 0; i < 8; ++i) {
            float s = 0.0f;
#pragma unroll
            for (int j = 0; j < 8; ++j) s = fmaf(R1[i * 8 + j], v[j], s);
            w[i] = s * inv[k];
        }
#pragma unroll
        for (int i = 0; i < 8; ++i) { v[i] = w[i]; y[i] += v[i]; }
    }

    float4* __restrict__ op = reinterpret_cast<float4*>(out + (size_t)tid * 8);
    op[0] = make_float4(y[0], y[1], y[2], y[3]);
    op[1] = make_float4(y[4], y[5], y[6], y[7]);
}

extern "C" void kernel_launch(void* const* d_in, const int* in_sizes, int n_in,
                              void* d_out, int out_size, void* d_ws, size_t ws_size,
                              hipStream_t stream)
{
    const float* A  = (const float*)d_in[0];
    const float* hp = (const float*)d_in[1];
    const float* y0 = (const float*)d_in[2];
    float* out = (float*)d_out;

    const int B = in_sizes[2] / 8;   // y0 is (B, 8)
    const int grid = (B + NT - 1) / NT;
    magnus6_kernel<<<grid, NT, 0, stream>>>(A, hp, y0, out, B);
}

// Round 4
// 51.087 us; speedup vs baseline: 1.2425x; 1.0047x over previous
//
#include <hip/hip_runtime.h>

#define NT 256

__device__ __forceinline__ void st4(float* dst, float4 v) {
    dst[0] = v.x; dst[1] = v.y; dst[2] = v.z; dst[3] = v.w;
}
__device__ __forceinline__ float4 ld4(const float* s) {
    return make_float4(s[0], s[1], s[2], s[3]);
}

// acc = X @ Y   (8x8, k=0 is mul not fma: no zero-init pass needed)
__device__ __forceinline__ void mm_mul(float (&acc)[64], const float (&X)[64], const float (&Y)[64]) {
#pragma unroll
    for (int i = 0; i < 8; ++i) {
        {
            const float x = X[i * 8 + 0];
#pragma unroll
            for (int j = 0; j < 8; ++j) acc[i * 8 + j] = x * Y[0 * 8 + j];
        }
#pragma unroll
        for (int k = 1; k < 8; ++k) {
            const float x = X[i * 8 + k];
#pragma unroll
            for (int j = 0; j < 8; ++j)
                acc[i * 8 + j] = fmaf(x, Y[k * 8 + j], acc[i * 8 + j]);
        }
    }
}
// acc += X @ Y
__device__ __forceinline__ void mm_add(float (&acc)[64], const float (&X)[64], const float (&Y)[64]) {
#pragma unroll
    for (int i = 0; i < 8; ++i) {
#pragma unroll
        for (int k = 0; k < 8; ++k) {
            const float x = X[i * 8 + k];
#pragma unroll
            for (int j = 0; j < 8; ++j)
                acc[i * 8 + j] = fmaf(x, Y[k * 8 + j], acc[i * 8 + j]);
        }
    }
}
// acc -= X @ Y
__device__ __forceinline__ void mm_sub(float (&acc)[64], const float (&X)[64], const float (&Y)[64]) {
#pragma unroll
    for (int i = 0; i < 8; ++i) {
#pragma unroll
        for (int k = 0; k < 8; ++k) {
            const float x = -X[i * 8 + k];
#pragma unroll
            for (int j = 0; j < 8; ++j)
                acc[i * 8 + j] = fmaf(x, Y[k * 8 + j], acc[i * 8 + j]);
        }
    }
}

__global__ __launch_bounds__(NT)
__attribute__((amdgpu_waves_per_eu(2, 2)))
void magnus6_kernel(const float* __restrict__ A,
                    const float* __restrict__ hp,
                    const float* __restrict__ y0,
                    float* __restrict__ out,
                    int B)
{
    // ONE per-thread-private spill slot (alpha3 only): 256 B/thread.
    // At NT=256 this is exactly 64 KB/block -> compiler's LDS-keyed occupancy
    // heuristic grants the big VGPR budget (proven no-spill regime, R1),
    // while runtime occupancy is 2 blocks x 4 waves = 8 waves/CU (2x R1).
    __shared__ float4 lds[16][NT];   // 64 KB

    const int tx  = threadIdx.x;
    const int tid = blockIdx.x * NT + tx;
    if (tid >= B) return;

    const float h    = hp[0];
    const float c_a2 = h * 1.2909944487358056f;   // h*sqrt(15)/3
    const float c_a3 = h * (10.0f / 3.0f);
    const float c_m  = 20.0f / 3.0f;

    const float4* __restrict__ Ap =
        reinterpret_cast<const float4*>(A + (size_t)tid * 192);

    float R1[64];   // alpha1 -> Omega0 -> Omega
    float R2[64];   // A1 -> alpha2 -> Q (commutator accumulated in place)
    float R3[64];   // C1 -> T' = (C1+2a3)/60 -> P' = term_in_comm/240

    // ---- load A1 -> R2 ----
#pragma unroll
    for (int c = 0; c < 16; ++c) st4(&R2[4 * c], Ap[c]);
    // ---- load A2, R1 = h*A2 = alpha1 ----
#pragma unroll
    for (int c = 0; c < 16; ++c) {
        float4 v = Ap[16 + c];
        R1[4 * c + 0] = h * v.x; R1[4 * c + 1] = h * v.y;
        R1[4 * c + 2] = h * v.z; R1[4 * c + 3] = h * v.w;
    }
    // ---- stream A3: alpha3 -> LDS ; alpha2 overwrites A1 in R2 ----
#pragma unroll
    for (int c = 0; c < 16; ++c) {
        float4 v = Ap[32 + c];
        float vv[4]; st4(vv, v);
        float w[4];
#pragma unroll
        for (int j = 0; j < 4; ++j) {
            const int idx = 4 * c + j;
            const float A1e = R2[idx];
            const float A3e = vv[j];
            w[j]    = c_a3 * (A1e + A3e) - c_m * R1[idx];  // alpha3 = h*10/3*(A1-2A2+A3)
            R2[idx] = c_a2 * (A3e - A1e);                  // alpha2
        }
        lds[c][tx] = ld4(w);
    }

    // ---- C1 = [alpha1, alpha2] into R3 ----
    mm_mul(R3, R1, R2);
    mm_sub(R3, R2, R1);

    // ---- T' = (C1 + 2*alpha3)/60  (in place; alpha3 streamed from LDS) ----
#pragma unroll
    for (int c = 0; c < 16; ++c) {
        float vv[4]; st4(vv, lds[c][tx]);
#pragma unroll
        for (int j = 0; j < 4; ++j) {
            const int idx = 4 * c + j;
            R3[idx] = fmaf(R3[idx], (1.0f / 60.0f), (1.0f / 30.0f) * vv[j]);
        }
    }

    // ---- Q = alpha2 - alpha1@T' + T'@alpha1  (accumulate in place into R2) ----
    //      (C2 = -(1/60)[alpha1, T] = -[alpha1, T'])
    mm_sub(R2, R1, R3);
    mm_add(R2, R3, R1);

    // ---- P' = T'/4 - alpha1/12 - alpha3/80  (into R3);
    //      Omega0 = alpha1 + alpha3/12        (into R1); alpha3 read once ----
#pragma unroll
    for (int c = 0; c < 16; ++c) {
        float vv[4]; st4(vv, lds[c][tx]);
#pragma unroll
        for (int j = 0; j < 4; ++j) {
            const int idx = 4 * c + j;
            const float a3e = vv[j];
            const float a1e = R1[idx];
            R3[idx] = 0.25f * R3[idx] - (1.0f / 12.0f) * a1e - (1.0f / 80.0f) * a3e;
            R1[idx] = a1e + (1.0f / 12.0f) * a3e;
        }
    }

    // ---- Omega = Omega0 + P'@Q - Q@P'  (accumulate into R1) ----
    mm_add(R1, R3, R2);
    mm_sub(R1, R2, R3);

    // ---- y = expm(Omega) @ y0 via Taylor matvecs (order 6) ----
    const float4* __restrict__ y0p =
        reinterpret_cast<const float4*>(y0 + (size_t)tid * 8);
    float v[8], y[8];
    st4(&v[0], y0p[0]); st4(&v[4], y0p[1]);
#pragma unroll
    for (int i = 0; i < 8; ++i) y[i] = v[i];

    const float inv[6] = {1.0f, 0.5f, 1.0f / 3.0f, 0.25f, 0.2f, 1.0f / 6.0f};
#pragma unroll
    for (int k = 0; k < 6; ++k) {
        float w[8];
#pragma unroll
        for (int i = 0; i < 8; ++i) {
            float s = 0.0f;
#pragma unroll
            for (int j = 0; j < 8; ++j) s = fmaf(R1[i * 8 + j], v[j], s);
            w[i] = s * inv[k];
        }
#pragma unroll
        for (int i = 0; i < 8; ++i) { v[i] = w[i]; y[i] += v[i]; }
    }

    float4* __restrict__ op = reinterpret_cast<float4*>(out + (size_t)tid * 8);
    op[0] = make_float4(y[0], y[1], y[2], y[3]);
    op[1] = make_float4(y[4], y[5], y[6], y[7]);
}

extern "C" void kernel_launch(void* const* d_in, const int* in_sizes, int n_in,
                              void* d_out, int out_size, void* d_ws, size_t ws_size,
                              hipStream_t stream)
{
    const float* A  = (const float*)d_in[0];
    const float* hp = (const float*)d_in[1];
    const float* y0 = (const float*)d_in[2];
    float* out = (float*)d_out;

    const int B = in_sizes[2] / 8;   // y0 is (B, 8)
    const int grid = (B + NT - 1) / NT;
    magnus6_kernel<<<grid, NT, 0, stream>>>(A, hp, y0, out, B);
}